// Round 4
// baseline (407.129 us; speedup 1.0000x reference)
//
#include <hip/hip_runtime.h>
#include <hip/hip_bf16.h>
#include <math.h>

// Problem constants (from reference): B=256, N=1024, H=256, K=5
#define BGRAPHS 256
#define NNODES  1024
#define HDIM    256
#define KSEL    5
#define NEG_SLOPE 0.01f

#define NPB    128   // nodes per block (1024/128 = 8 blocks per graph, block never spans graphs)
#define UNROLL 4     // nodes in flight per wave

// ---------------------------------------------------------------------------
// Kernel 1: per-node max over H=256 f32 channels -> keys[node], masked to
// -inf for padded nodes. 2048 blocks x 256 threads; each block owns 128
// consecutive nodes of ONE graph. Per iteration the 4 waves read a contiguous
// 4 KiB strip (wave w = node base+i*4+w, lane l = float4 #l of that node).
// UNROLL=4 keeps 4 float4 loads in flight per wave before the reduces.
// Keys staged in LDS, then written coalesced (512 B/block).
// ---------------------------------------------------------------------------
__global__ __launch_bounds__(256) void node_max_kernel(
        const float* __restrict__ h,
        const int* __restrict__ n_nodes,
        float* __restrict__ keys) {
    __shared__ float keys_s[NPB];
    const int t    = threadIdx.x;
    const int wave = t >> 6;
    const int lane = t & 63;

    const long long base = (long long)blockIdx.x * NPB;   // first node of block
    const int b   = (int)(base >> 10);                    // graph id (block-uniform)
    const int nn  = n_nodes[b];                           // scalar load
    const int nb0 = (int)(base & 1023);                   // node-in-graph of keys_s[0]

    const float4* __restrict__ h4 = (const float4*)h;
    // float4 index for (node, lane): node*64 + lane
    long long idx = (base + wave) * 64 + lane;

    for (int ii = 0; ii < NPB / 4; ii += UNROLL) {
        float4 d[UNROLL];
#pragma unroll
        for (int u = 0; u < UNROLL; ++u)
            d[u] = h4[idx + (long long)(ii + u) * 4 * 64];
#pragma unroll
        for (int u = 0; u < UNROLL; ++u) {
            float m = fmaxf(fmaxf(d[u].x, d[u].y), fmaxf(d[u].z, d[u].w));
#pragma unroll
            for (int off = 32; off > 0; off >>= 1)
                m = fmaxf(m, __shfl_xor(m, off, 64));
            if (lane == 0) {
                int local = (ii + u) * 4 + wave;          // 0..127 within block
                keys_s[local] = (nb0 + local < nn) ? m : -INFINITY;
            }
        }
    }
    __syncthreads();
    if (t < NPB)
        keys[base + t] = keys_s[t];                       // coalesced 512 B store
}

// ---------------------------------------------------------------------------
// Kernel 2: one block (256 threads) per graph.
//   top-5 by (key desc, idx asc)  [jax.lax.top_k stable tie-break]
//   gather the 5 rows, rank-sort each ascending (jnp.sort)
//   logit_k = leaky_relu(dot(sorted_k, W1) + dot(q, W2)); softmax over K;
//   out = sum_k atten_k * sorted_k. Invalid rows (key==-inf) are zeroed but
//   STILL participate in the softmax (matches reference semantics; duplicate
//   -inf picks are benign because those rows are zeroed).
// ---------------------------------------------------------------------------
__global__ __launch_bounds__(256) void topk_attn_kernel(
        const float* __restrict__ h,
        const float* __restrict__ q,
        const float* __restrict__ W,    // [2H] flat: W1 = W[0:H], W2 = W[H:2H]
        const float* __restrict__ keys,
        float* __restrict__ out) {
    __shared__ float keys_s[NNODES];
    __shared__ float red_v[256];
    __shared__ int   red_i[256];
    __shared__ float sorted_s[KSEL][HDIM];
    __shared__ float vals_s[HDIM];
    __shared__ float dots[KSEL];
    __shared__ float atten[KSEL];
    __shared__ float cb_s;
    __shared__ int   top_idx[KSEL];
    __shared__ float top_val[KSEL];

    const int t = threadIdx.x;
    const int b = blockIdx.x;

    // ---- load this graph's keys into LDS (coalesced) ----
#pragma unroll
    for (int i = 0; i < 4; ++i)
        keys_s[t + 256 * i] = keys[b * NNODES + t + 256 * i];

    // ---- c_b = dot(q_b, W2) ----
    red_v[t] = q[b * HDIM + t] * W[HDIM + t];
    __syncthreads();
    for (int s = 128; s > 0; s >>= 1) {
        if (t < s) red_v[t] += red_v[t + s];
        __syncthreads();
    }
    if (t == 0) cb_s = red_v[0];
    __syncthreads();

    // ---- top-5: 5 x block argmax with (val desc, idx asc) ordering ----
    for (int k = 0; k < KSEL; ++k) {
        float bv = -INFINITY;
        int   bi = 0x7fffffff;
#pragma unroll
        for (int i = 0; i < 4; ++i) {
            int j = t * 4 + i;
            float v = keys_s[j];
            if (v > bv || (v == bv && j < bi)) { bv = v; bi = j; }
        }
        red_v[t] = bv;
        red_i[t] = bi;
        __syncthreads();
        for (int s = 128; s > 0; s >>= 1) {
            if (t < s) {
                float ov = red_v[t + s];
                int   oi = red_i[t + s];
                if (ov > red_v[t] || (ov == red_v[t] && oi < red_i[t])) {
                    red_v[t] = ov;
                    red_i[t] = oi;
                }
            }
            __syncthreads();
        }
        if (t == 0) {
            top_idx[k] = red_i[0];
            top_val[k] = red_v[0];
            keys_s[red_i[0]] = -INFINITY;   // exclude for next round
        }
        __syncthreads();
    }

    // ---- gather + rank-sort each selected row (ascending) ----
    for (int k = 0; k < KSEL; ++k) {
        int  sel   = top_idx[k];
        bool valid = (top_val[k] != -INFINITY);
        float v = 0.0f;
        if (valid)
            v = h[((long long)b * NNODES + sel) * HDIM + t];
        vals_s[t] = v;
        __syncthreads();
        int rank = 0;
        for (int j = 0; j < HDIM; ++j) {
            float vj = vals_s[j];                       // broadcast read, conflict-free
            rank += (vj < v) || (vj == v && j < t);     // total order -> bijection
        }
        sorted_s[k][rank] = v;
        __syncthreads();
    }

    // ---- logits: dot(sorted_k, W1) via block reduce ----
    float w1 = W[t];
    for (int k = 0; k < KSEL; ++k) {
        red_v[t] = sorted_s[k][t] * w1;
        __syncthreads();
        for (int s = 128; s > 0; s >>= 1) {
            if (t < s) red_v[t] += red_v[t + s];
            __syncthreads();
        }
        if (t == 0) dots[k] = red_v[0];
        __syncthreads();
    }

    // ---- leaky-relu + softmax over K (thread 0) ----
    if (t == 0) {
        float lg[KSEL];
        float mx = -INFINITY;
#pragma unroll
        for (int k = 0; k < KSEL; ++k) {
            float x = dots[k] + cb_s;        // invalid rows: dot==0 -> x=c_b
            lg[k] = (x > 0.0f) ? x : NEG_SLOPE * x;
            mx = fmaxf(mx, lg[k]);
        }
        float den = 0.0f;
#pragma unroll
        for (int k = 0; k < KSEL; ++k) { lg[k] = expf(lg[k] - mx); den += lg[k]; }
#pragma unroll
        for (int k = 0; k < KSEL; ++k) atten[k] = lg[k] / den;
    }
    __syncthreads();

    // ---- weighted sum, f32 store ----
    float o = 0.0f;
#pragma unroll
    for (int k = 0; k < KSEL; ++k)
        o += atten[k] * sorted_s[k][t];

    out[b * HDIM + t] = o;
}

extern "C" void kernel_launch(void* const* d_in, const int* in_sizes, int n_in,
                              void* d_out, int out_size, void* d_ws, size_t ws_size,
                              hipStream_t stream) {
    // Inputs (setup_inputs order, reference dtypes): h [B,N,H] f32,
    // n_nodes [B] int32, attention_query [B,H] f32, W [1,2H] f32.
    // Output: [B,H] f32.
    const float* h  = (const float*)d_in[0];
    const int*   nn = (const int*)d_in[1];
    const float* q  = (const float*)d_in[2];
    const float* W  = (const float*)d_in[3];
    float*       out = (float*)d_out;

    float* keys = (float*)d_ws;   // B*N floats = 1 MiB, fully overwritten every call

    // Pass 1: per-node max (memory-bound: reads 268 MB f32).
    // 2048 blocks (8/CU, full 32-wave occupancy), 128 nodes/block.
    node_max_kernel<<<(BGRAPHS * NNODES) / NPB, 256, 0, stream>>>(h, nn, keys);
    // Pass 2: per-graph top-5 + sort + attention (tiny)
    topk_attn_kernel<<<BGRAPHS, 256, 0, stream>>>(h, q, W, keys, out);
}

// Round 5
// 375.750 us; speedup vs baseline: 1.0835x; 1.0835x over previous
//
#include <hip/hip_runtime.h>
#include <hip/hip_bf16.h>
#include <math.h>

// Problem constants (from reference): B=256, N=1024, H=256, K=5
#define BGRAPHS 256
#define NNODES  1024
#define HDIM    256
#define KSEL    5
#define NEG_SLOPE 0.01f

#define NPB    128   // nodes per block (1024/128 = 8 blocks per graph, block never spans graphs)
#define UNROLL 4     // iterations (4 nodes each) in flight per wave

// ---------------------------------------------------------------------------
// Kernel 1: per-node max over H=256 f32 channels -> keys[node]; -inf for
// padded nodes. 2048 blocks x 256 threads; each block owns 128 consecutive
// nodes of ONE graph. KEY OPTIMIZATION: n_nodes[b] is block-uniform, so the
// block clamps its work to the valid prefix and never issues loads for
// padded nodes (expected ~50% of h is padding -> ~134 MB read, not 268 MB).
// The skip predicate depends only on (ii, wave) -> wave-uniform, no
// divergence. Keys staged in LDS (pre-filled -inf), coalesced 512 B store.
// ---------------------------------------------------------------------------
__global__ __launch_bounds__(256) void node_max_kernel(
        const float* __restrict__ h,
        const int* __restrict__ n_nodes,
        float* __restrict__ keys) {
    __shared__ float keys_s[NPB];
    const int t    = threadIdx.x;
    const int wave = t >> 6;
    const int lane = t & 63;

    const long long base = (long long)blockIdx.x * NPB;   // first node of block
    const int b   = (int)(base >> 10);                    // graph id (block-uniform)
    const int nb0 = (int)(base & 1023);                   // node-in-graph of keys_s[0]
    int nv = n_nodes[b] - nb0;                            // valid nodes in this block
    nv = nv < 0 ? 0 : (nv > NPB ? NPB : nv);

    if (t < NPB) keys_s[t] = -INFINITY;                   // tail default
    __syncthreads();

    const float4* __restrict__ h4 = (const float4*)h;
    // float4 index for (node, lane): node*64 + lane
    const long long idx = (base + wave) * 64 + lane;

    // Each iteration ii covers nodes [ii*4, ii*4+4) (one per wave).
    const int niter = (nv + 3) >> 2;                      // only valid prefix
    for (int ii = 0; ii < niter; ii += UNROLL) {
        float4 d[UNROLL];
        bool   act[UNROLL];
#pragma unroll
        for (int u = 0; u < UNROLL; ++u) {
            int local = (ii + u) * 4 + wave;              // wave-uniform
            act[u] = (local < nv) && (ii + u < niter);
            if (act[u])
                d[u] = h4[idx + (long long)(ii + u) * 4 * 64];
        }
#pragma unroll
        for (int u = 0; u < UNROLL; ++u) {
            if (act[u]) {                                 // wave-uniform branch
                float m = fmaxf(fmaxf(d[u].x, d[u].y), fmaxf(d[u].z, d[u].w));
#pragma unroll
                for (int off = 32; off > 0; off >>= 1)
                    m = fmaxf(m, __shfl_xor(m, off, 64));
                if (lane == 0)
                    keys_s[(ii + u) * 4 + wave] = m;
            }
        }
    }
    __syncthreads();
    if (t < NPB)
        keys[base + t] = keys_s[t];                       // coalesced 512 B store
}

// ---------------------------------------------------------------------------
// Kernel 2: one block (256 threads) per graph.
//   top-5 by (key desc, idx asc)  [jax.lax.top_k stable tie-break]
//   gather the 5 rows, rank-sort each ascending (jnp.sort)
//   logit_k = leaky_relu(dot(sorted_k, W1) + dot(q, W2)); softmax over K;
//   out = sum_k atten_k * sorted_k. Invalid rows (key==-inf) are zeroed but
//   STILL participate in the softmax (matches reference semantics; duplicate
//   -inf picks are benign because those rows are zeroed).
// ---------------------------------------------------------------------------
__global__ __launch_bounds__(256) void topk_attn_kernel(
        const float* __restrict__ h,
        const float* __restrict__ q,
        const float* __restrict__ W,    // [2H] flat: W1 = W[0:H], W2 = W[H:2H]
        const float* __restrict__ keys,
        float* __restrict__ out) {
    __shared__ float keys_s[NNODES];
    __shared__ float red_v[256];
    __shared__ int   red_i[256];
    __shared__ float sorted_s[KSEL][HDIM];
    __shared__ float vals_s[HDIM];
    __shared__ float dots[KSEL];
    __shared__ float atten[KSEL];
    __shared__ float cb_s;
    __shared__ int   top_idx[KSEL];
    __shared__ float top_val[KSEL];

    const int t = threadIdx.x;
    const int b = blockIdx.x;

    // ---- load this graph's keys into LDS (coalesced) ----
#pragma unroll
    for (int i = 0; i < 4; ++i)
        keys_s[t + 256 * i] = keys[b * NNODES + t + 256 * i];

    // ---- c_b = dot(q_b, W2) ----
    red_v[t] = q[b * HDIM + t] * W[HDIM + t];
    __syncthreads();
    for (int s = 128; s > 0; s >>= 1) {
        if (t < s) red_v[t] += red_v[t + s];
        __syncthreads();
    }
    if (t == 0) cb_s = red_v[0];
    __syncthreads();

    // ---- top-5: 5 x block argmax with (val desc, idx asc) ordering ----
    for (int k = 0; k < KSEL; ++k) {
        float bv = -INFINITY;
        int   bi = 0x7fffffff;
#pragma unroll
        for (int i = 0; i < 4; ++i) {
            int j = t * 4 + i;
            float v = keys_s[j];
            if (v > bv || (v == bv && j < bi)) { bv = v; bi = j; }
        }
        red_v[t] = bv;
        red_i[t] = bi;
        __syncthreads();
        for (int s = 128; s > 0; s >>= 1) {
            if (t < s) {
                float ov = red_v[t + s];
                int   oi = red_i[t + s];
                if (ov > red_v[t] || (ov == red_v[t] && oi < red_i[t])) {
                    red_v[t] = ov;
                    red_i[t] = oi;
                }
            }
            __syncthreads();
        }
        if (t == 0) {
            top_idx[k] = red_i[0];
            top_val[k] = red_v[0];
            keys_s[red_i[0]] = -INFINITY;   // exclude for next round
        }
        __syncthreads();
    }

    // ---- gather + rank-sort each selected row (ascending) ----
    for (int k = 0; k < KSEL; ++k) {
        int  sel   = top_idx[k];
        bool valid = (top_val[k] != -INFINITY);
        float v = 0.0f;
        if (valid)
            v = h[((long long)b * NNODES + sel) * HDIM + t];
        vals_s[t] = v;
        __syncthreads();
        int rank = 0;
        for (int j = 0; j < HDIM; ++j) {
            float vj = vals_s[j];                       // broadcast read, conflict-free
            rank += (vj < v) || (vj == v && j < t);     // total order -> bijection
        }
        sorted_s[k][rank] = v;
        __syncthreads();
    }

    // ---- logits: dot(sorted_k, W1) via block reduce ----
    float w1 = W[t];
    for (int k = 0; k < KSEL; ++k) {
        red_v[t] = sorted_s[k][t] * w1;
        __syncthreads();
        for (int s = 128; s > 0; s >>= 1) {
            if (t < s) red_v[t] += red_v[t + s];
            __syncthreads();
        }
        if (t == 0) dots[k] = red_v[0];
        __syncthreads();
    }

    // ---- leaky-relu + softmax over K (thread 0) ----
    if (t == 0) {
        float lg[KSEL];
        float mx = -INFINITY;
#pragma unroll
        for (int k = 0; k < KSEL; ++k) {
            float x = dots[k] + cb_s;        // invalid rows: dot==0 -> x=c_b
            lg[k] = (x > 0.0f) ? x : NEG_SLOPE * x;
            mx = fmaxf(mx, lg[k]);
        }
        float den = 0.0f;
#pragma unroll
        for (int k = 0; k < KSEL; ++k) { lg[k] = expf(lg[k] - mx); den += lg[k]; }
#pragma unroll
        for (int k = 0; k < KSEL; ++k) atten[k] = lg[k] / den;
    }
    __syncthreads();

    // ---- weighted sum, f32 store ----
    float o = 0.0f;
#pragma unroll
    for (int k = 0; k < KSEL; ++k)
        o += atten[k] * sorted_s[k][t];

    out[b * HDIM + t] = o;
}

extern "C" void kernel_launch(void* const* d_in, const int* in_sizes, int n_in,
                              void* d_out, int out_size, void* d_ws, size_t ws_size,
                              hipStream_t stream) {
    // Inputs (setup_inputs order, reference dtypes): h [B,N,H] f32,
    // n_nodes [B] int32, attention_query [B,H] f32, W [1,2H] f32.
    // Output: [B,H] f32.
    const float* h  = (const float*)d_in[0];
    const int*   nn = (const int*)d_in[1];
    const float* q  = (const float*)d_in[2];
    const float* W  = (const float*)d_in[3];
    float*       out = (float*)d_out;

    float* keys = (float*)d_ws;   // B*N floats = 1 MiB, fully overwritten every call

    // Pass 1: per-node max, reading ONLY the valid node prefix per graph
    // (expected ~134 MB of the 268 MB h). 2048 blocks, 128 nodes/block.
    node_max_kernel<<<(BGRAPHS * NNODES) / NPB, 256, 0, stream>>>(h, nn, keys);
    // Pass 2: per-graph top-5 + sort + attention (tiny)
    topk_attn_kernel<<<BGRAPHS, 256, 0, stream>>>(h, q, W, keys, out);
}